// Round 2
// baseline (309.169 us; speedup 1.0000x reference)
//
#include <hip/hip_runtime.h>
#include <hip/hip_bf16.h>
#include <cstddef>

#define D_DIM 768
#define V_DIM 10240
#define ROWS  32768          // B*N = 8*4096
#define BM    64             // rows per block
#define BN    384            // cols per block (2 col-blocks cover N=768)
#define BK    32
#define KTILES (D_DIM / BK)  // 24

using bf16x8 = __attribute__((ext_vector_type(8))) __bf16;
using bf16x4 = __attribute__((ext_vector_type(4))) __bf16;
using f32x4  = __attribute__((ext_vector_type(4))) float;

// ---------------------------------------------------------------------------
// Pre-pass: fold permutation + 2*(x-0.5) affine into weights.
// W'[d][j] = 2 * W[d][perm(j)],  perm(j) = (j%3)*256 + (j/48)*16 + (j/3)%16
// bias[d]  = -sum_k W[d][k]
// ---------------------------------------------------------------------------
__global__ void prep_w(const float* __restrict__ W, __bf16* __restrict__ Wp,
                       float* __restrict__ bias) {
    __shared__ float row[D_DIM];
    __shared__ float red[256];
    const int d = blockIdx.x;
    const int t = threadIdx.x;
    float s = 0.f;
    for (int k = t; k < D_DIM; k += 256) {
        float w = W[(size_t)d * D_DIM + k];
        row[k] = w;
        s += w;
    }
    red[t] = s;
    __syncthreads();
    for (int off = 128; off > 0; off >>= 1) {
        if (t < off) red[t] += red[t + off];
        __syncthreads();
    }
    if (t == 0) bias[d] = -red[0];
    for (int j = t; j < D_DIM; j += 256) {
        int c  = j % 3;
        int pw = (j / 3) & 15;
        int ph = j / 48;
        Wp[(size_t)d * D_DIM + j] = (__bf16)(2.0f * row[c * 256 + ph * 16 + pw]);
    }
}

// ---------------------------------------------------------------------------
// Fused GEMM: BM=64 rows x BN=384 cols per block, 8 waves (2x4), acc[2][6].
//  - LDS 56 KB -> 2 blocks/CU; VGPR capped <=128 via __launch_bounds__(512,4).
//  - K-loop unrolled by 2 with LITERAL buffer indices so the compiler can
//    disambiguate lb[0] reads from lb[1] global_load_lds writes and overlap.
//  - Pair-preserving XCD swizzle: both col-blocks of a row panel land on the
//    same XCD so the 2nd X read is an L2 hit.
// Swizzle: 16B-unit u' = u ^ ((row>>1)&3) within the 64B row (inverse-swz
// source for global_load_lds, swz applied on ds_read and on reg-staged A).
// ---------------------------------------------------------------------------
__launch_bounds__(512, 4)
__global__ void gemm_fused(const float* __restrict__ X, const __bf16* __restrict__ Wp,
                           const float* __restrict__ bias, const float* __restrict__ ptab,
                           const int* __restrict__ coord, const int* __restrict__ valid,
                           float* __restrict__ out0, float* __restrict__ out1,
                           float* __restrict__ out2) {
    __shared__ __align__(16) __bf16 la[2][BM * BK];   // 2 x 4 KB
    __shared__ __align__(16) __bf16 lb[2][BN * BK];   // 2 x 24 KB

    const int tid  = threadIdx.x;
    const int lane = tid & 63;
    const int wave = tid >> 6;
    const int wr   = (wave >> 2) * 32;   // 2 row groups
    const int wc   = (wave & 3) * 96;    // 4 col groups
    const int lr   = lane & 15;
    const int qh   = lane >> 4;          // 16B k-unit index

    // XCD swizzle (1024 % 8 == 0 -> bijective); keep (bx0,bx1) pairs together.
    const int id = blockIdx.x;
    const int w  = (id & 7) * 128 + (id >> 3);
    const int bx = w & 1;
    const int by = w >> 1;
    const int m0 = by * BM;
    const int n0 = bx * BN;

    // Aux outputs: each row panel handled once (col-block 0).
    if (bx == 0 && tid < BM) {
        int m  = m0 + tid;
        int c0 = coord[2 * m];
        int c1 = coord[2 * m + 1];
        out1[2 * m]     = (float)c1;
        out1[2 * m + 1] = (float)c0;
        out2[m] = valid[m] ? 0.0f : 1.0f;
    }

    // ---- B staging: 1536 16B-units, 3 global_load_lds per thread ----
    const __bf16* bsrc0; const __bf16* bsrc1; const __bf16* bsrc2;
    int bdst0, bdst1, bdst2;
    {
        int q, row, su;
        q = tid;           row = q >> 2; su = (q & 3) ^ ((row >> 1) & 3);
        bsrc0 = Wp + (size_t)(n0 + row) * D_DIM + su * 8;  bdst0 = q * 8;
        q = 512 + tid;     row = q >> 2; su = (q & 3) ^ ((row >> 1) & 3);
        bsrc1 = Wp + (size_t)(n0 + row) * D_DIM + su * 8;  bdst1 = q * 8;
        q = 1024 + tid;    row = q >> 2; su = (q & 3) ^ ((row >> 1) & 3);
        bsrc2 = Wp + (size_t)(n0 + row) * D_DIM + su * 8;  bdst2 = q * 8;
    }

    // ---- A staging: 1 float4 -> bf16x4 per thread ----
    const int a_row = tid >> 3;                       // 0..63
    const int a_u   = (tid & 7) >> 1;
    const int a_h   = tid & 1;
    const int a_off = a_row * BK + (a_u ^ ((a_row >> 1) & 3)) * 8 + a_h * 4;
    const float* asrc = X + (size_t)(m0 + a_row) * D_DIM + ((tid & 7) << 2);

    // ---- fragment read offsets (swizzled) ----
    int aoff0, aoff1, boff[6];
    {
        int row = wr + lr;
        aoff0 = row * BK + (qh ^ ((row >> 1) & 3)) * 8;
        row = wr + 16 + lr;
        aoff1 = row * BK + (qh ^ ((row >> 1) & 3)) * 8;
    }
    #pragma unroll
    for (int j = 0; j < 6; ++j) {
        int row = wc + j * 16 + lr;
        boff[j] = row * BK + (qh ^ ((row >> 1) & 3)) * 8;
    }

    f32x4 acc[2][6] = {};

#define STAGE(BUF, KT)                                                          \
    do {                                                                        \
        const int k0_ = (KT) * BK;                                              \
        __builtin_amdgcn_global_load_lds(                                       \
            (const __attribute__((address_space(1))) void*)(bsrc0 + k0_),       \
            (__attribute__((address_space(3))) void*)&lb[BUF][bdst0], 16, 0, 0);\
        __builtin_amdgcn_global_load_lds(                                       \
            (const __attribute__((address_space(1))) void*)(bsrc1 + k0_),       \
            (__attribute__((address_space(3))) void*)&lb[BUF][bdst1], 16, 0, 0);\
        __builtin_amdgcn_global_load_lds(                                       \
            (const __attribute__((address_space(1))) void*)(bsrc2 + k0_),       \
            (__attribute__((address_space(3))) void*)&lb[BUF][bdst2], 16, 0, 0);\
        float4 f_ = *(const float4*)(asrc + k0_);                               \
        bf16x4 v_;                                                              \
        v_[0] = (__bf16)f_.x; v_[1] = (__bf16)f_.y;                             \
        v_[2] = (__bf16)f_.z; v_[3] = (__bf16)f_.w;                             \
        *(bf16x4*)&la[BUF][a_off] = v_;                                         \
    } while (0)

#define COMPUTE(BUF)                                                            \
    do {                                                                        \
        bf16x8 af0_ = *(const bf16x8*)&la[BUF][aoff0];                          \
        bf16x8 af1_ = *(const bf16x8*)&la[BUF][aoff1];                          \
        _Pragma("unroll")                                                       \
        for (int j = 0; j < 6; ++j) {                                           \
            bf16x8 bv_ = *(const bf16x8*)&lb[BUF][boff[j]];                     \
            acc[0][j] = __builtin_amdgcn_mfma_f32_16x16x32_bf16(af0_, bv_, acc[0][j], 0, 0, 0); \
            acc[1][j] = __builtin_amdgcn_mfma_f32_16x16x32_bf16(af1_, bv_, acc[1][j], 0, 0, 0); \
        }                                                                       \
    } while (0)

    // prologue
    STAGE(0, 0);
    __syncthreads();

    for (int kt = 0; kt < KTILES; kt += 2) {
        STAGE(1, kt + 1);            // kt+1 <= 23 always (KTILES even)
        COMPUTE(0);
        __syncthreads();
        if (kt + 2 < KTILES) STAGE(0, kt + 2);
        COMPUTE(1);
        __syncthreads();
    }

#undef STAGE
#undef COMPUTE

    // ---- epilogue: bias + pos add + store ----
    const float* pt0 = ptab;
    const float* pt1 = ptab + (size_t)V_DIM * D_DIM;

    float bv[6];
    #pragma unroll
    for (int j = 0; j < 6; ++j)
        bv[j] = bias[n0 + wc + j * 16 + lr];

    #pragma unroll
    for (int i = 0; i < 2; ++i) {
        #pragma unroll
        for (int r = 0; r < 4; ++r) {
            const int m = m0 + wr + i * 16 + qh * 4 + r;
            int c0 = coord[2 * m];
            int c1 = coord[2 * m + 1];
            if (c0 < 0) c0 = 0;
            if (c1 < 0) c1 = 0;
            const int vld = valid[m];
            const float* p0 = pt0 + (size_t)c1 * D_DIM;
            const float* p1 = pt1 + (size_t)c0 * D_DIM;
            float* orow = out0 + (size_t)m * D_DIM;
            #pragma unroll
            for (int j = 0; j < 6; ++j) {
                const int d = n0 + wc + j * 16 + lr;
                float v = acc[i][j][r] + bv[j];
                if (vld)
                    v += p0[d] + p1[d];
                orow[d] = v;
            }
        }
    }
}

extern "C" void kernel_launch(void* const* d_in, const int* in_sizes, int n_in,
                              void* d_out, int out_size, void* d_ws, size_t ws_size,
                              hipStream_t stream) {
    const float* x     = (const float*)d_in[0];
    const int*   coord = (const int*)d_in[1];
    const int*   valid = (const int*)d_in[2];
    const float* W     = (const float*)d_in[3];
    const float* ptab  = (const float*)d_in[4];

    float* out0 = (float*)d_out;                  // [32768][768]
    float* out1 = out0 + (size_t)ROWS * D_DIM;    // [32768][2]
    float* out2 = out1 + (size_t)ROWS * 2;        // [32768]

    // Workspace: [Wp bf16 1.125 MB][bias 3 KB]
    __bf16* Wp   = (__bf16*)d_ws;
    float*  bias = (float*)((char*)d_ws + (size_t)D_DIM * D_DIM * sizeof(__bf16));

    hipLaunchKernelGGL(prep_w, dim3(D_DIM), dim3(256), 0, stream, W, Wp, bias);
    hipLaunchKernelGGL(gemm_fused, dim3((ROWS / BM) * (D_DIM / BN)), dim3(512), 0, stream,
                       x, Wp, bias, ptab, coord, valid, out0, out1, out2);
}